// Round 6
// baseline (1061.396 us; speedup 1.0000x reference)
//
#include <hip/hip_runtime.h>

// VectorQuantizer: z (8,64,16,64,64) f32, emb (512,64) f32.
// N = 524288, D = 64, K = 512.
// out flat = [ z_q_st (33554432 f32) | loss (1 f32) | indices (524288 f32) ]
//
// Bit-exact replication of the checker's np fp32 arithmetic (verified R3):
//   d[n,k] = fl( fmaf(-2, M_nk, zz_n) + ee_k ),  M_nk = sequential fma chain
//   c=0..63; zz/ee = numpy pairwise sum-of-squares (n=64 pattern);
//   argmin = strict <, ascending k.
//
// R11: R9/R10 identified the true bound: LDS INSTRUCTION THROUGHPUT.
// Uniform-broadcast ds_read_b128 moves 16B/instr; the DS pipe is per-CU
// (shared by 4 SIMDs) at ~12cyc/instr. R=2 rows/thread -> 16 waves/CU x
// 8192 DS instr x 12cy = 655us model vs 617 measured. DS cost = 1310/R us;
// VALU floor 218us. R=4 rows/thread halves DS to 327us with exactly 2048
// waves (2/SIMD, perfectly balanced); R=6 is ragged, R=8 needs 512 z-regs.
// waves_per_eu(1,1) gives the 512-reg budget for zr[4][64] (~300 live;
// overflow lands in AGPRs, which gfx950 VALU reads directly as operands).
// ee reads batched 1x b128 per 4 k. Predicted ~340-370us DS-bound.

#define NK       512
#define DD       64
#define LOSS_OFF 33554432
#define IDX_OFF  33554433
#define EE_FOFF  4            // float offset of ee[512] in ws (byte 16)

typedef float f32x4 __attribute__((ext_vector_type(4)));

// numpy pairwise_sum of squares, n=64: 8 strided accumulators combined
// ((r0+r1)+(r2+r3))+((r4+r5)+(r6+r7)); squares rounded separately
// (contract(off) keeps square and add separately rounded).
__device__ __forceinline__ float np_sumsq64(const float* v) {
#pragma clang fp contract(off)
    float r[8];
    #pragma unroll
    for (int j = 0; j < 8; ++j) {
        float s = v[j] * v[j];
        r[j] = s;
    }
    #pragma unroll
    for (int i = 8; i < 64; i += 8) {
        #pragma unroll
        for (int j = 0; j < 8; ++j) {
            float s = v[i + j] * v[i + j];
            r[j] += s;
        }
    }
    return ((r[0] + r[1]) + (r[2] + r[3])) + ((r[4] + r[5]) + (r[6] + r[7]));
}

__global__ void vq_ee(const float* __restrict__ emb, float* __restrict__ ws) {
    const int k = blockIdx.x * 256 + threadIdx.x;      // grid 2 x 256
    if (blockIdx.x == 0 && threadIdx.x == 0) {         // zero fp64 loss acc
        ((double*)ws)[0] = 0.0;
        ((double*)ws)[1] = 0.0;
    }
    float row[DD];
    const float* er = emb + k * DD;
    #pragma unroll
    for (int c = 0; c < DD; ++c) row[c] = er[c];
    ws[EE_FOFF + k] = np_sumsq64(row);
}

__global__ __launch_bounds__(256)
__attribute__((amdgpu_waves_per_eu(1, 1)))
void vq_main(const float* __restrict__ z, const float* __restrict__ emb,
             float* __restrict__ out, float* __restrict__ ws) {
    __shared__ f32x4 elds[2048];       // 32 KB: 128 emb rows per pass
    __shared__ f32x4 eelds4[128];      // 2 KB: ee[512] as 128 x f32x4

    const int tid = threadIdx.x;
    const int blk = blockIdx.x;                        // grid 512 x 256
    const int b   = blk >> 6;                          // 1024 | 65536: no straddle
    const int sp0 = (blk & 63) * 1024 + tid;           // rows j at sp0 + j*256
    const float* zb = z + ((size_t)b << 22);

    if (tid < 128)                                     // stage ee once
        eelds4[tid] = ((const f32x4*)(ws + EE_FOFF))[tid];

    float zr[4][DD];                                   // 256 regs (V+A unified)
    #pragma unroll
    for (int j = 0; j < 4; ++j)
        #pragma unroll
        for (int c = 0; c < DD; ++c)
            zr[j][c] = zb[sp0 + j * 256 + ((size_t)c << 16)];
    float zz[4];
    #pragma unroll
    for (int j = 0; j < 4; ++j) zz[j] = np_sumsq64(zr[j]);

    const f32x4* eg = (const f32x4*)emb;

    float best0 = 3.4e38f, best1 = 3.4e38f, best2 = 3.4e38f, best3 = 3.4e38f;
    int   bi0 = 0, bi1 = 0, bi2 = 0, bi3 = 0;

    #pragma unroll 1
    for (int p = 0; p < 4; ++p) {
        __syncthreads();                               // prev pass reads done
        #pragma unroll
        for (int r = 0; r < 8; ++r)                    // 32 KB coalesced fill
            elds[r * 256 + tid] = eg[p * 2048 + r * 256 + tid];
        __syncthreads();                               // fill visible

        #pragma unroll 1
        for (int ko = 0; ko < 32; ++ko) {              // 4 k per iteration
            const f32x4 ee4 = eelds4[p * 32 + ko];
            #pragma unroll
            for (int ki = 0; ki < 4; ++ki) {
                const int kl = ko * 4 + ki;
                float m0 = 0.f, m1 = 0.f, m2 = 0.f, m3 = 0.f;
                #pragma unroll
                for (int c4 = 0; c4 < 16; ++c4) {
                    const f32x4 e = elds[kl * 16 + c4];  // uniform broadcast
                    const int c = c4 * 4;
                    m0 = fmaf(zr[0][c+0], e.x, m0); m1 = fmaf(zr[1][c+0], e.x, m1);
                    m2 = fmaf(zr[2][c+0], e.x, m2); m3 = fmaf(zr[3][c+0], e.x, m3);
                    m0 = fmaf(zr[0][c+1], e.y, m0); m1 = fmaf(zr[1][c+1], e.y, m1);
                    m2 = fmaf(zr[2][c+1], e.y, m2); m3 = fmaf(zr[3][c+1], e.y, m3);
                    m0 = fmaf(zr[0][c+2], e.z, m0); m1 = fmaf(zr[1][c+2], e.z, m1);
                    m2 = fmaf(zr[2][c+2], e.z, m2); m3 = fmaf(zr[3][c+2], e.z, m3);
                    m0 = fmaf(zr[0][c+3], e.w, m0); m1 = fmaf(zr[1][c+3], e.w, m1);
                    m2 = fmaf(zr[2][c+3], e.w, m2); m3 = fmaf(zr[3][c+3], e.w, m3);
                }
                const int k = p * 128 + kl;            // ascending global k
                const float ee = (ki == 0) ? ee4.x : (ki == 1) ? ee4.y
                               : (ki == 2) ? ee4.z : ee4.w;
                const float d0 = fmaf(-2.f, m0, zz[0]) + ee;
                const float d1 = fmaf(-2.f, m1, zz[1]) + ee;
                const float d2 = fmaf(-2.f, m2, zz[2]) + ee;
                const float d3 = fmaf(-2.f, m3, zz[3]) + ee;
                if (d0 < best0) { best0 = d0; bi0 = k; }   // strict <, asc k
                if (d1 < best1) { best1 = d1; bi1 = k; }
                if (d2 < best2) { best2 = d2; bi2 = k; }
                if (d3 < best3) { best3 = d3; bi3 = k; }
            }
        }
    }

    // epilogue x4: gather z_q rows (emb L2-hot, divergent bi), coalesced writes
    float* ob = out + ((size_t)b << 22);
    const int bis[4] = { bi0, bi1, bi2, bi3 };
    float lsum = 0.f;
    #pragma unroll
    for (int j = 0; j < 4; ++j) {
        float* op = ob + sp0 + j * 256;
        const float4* brow = (const float4*)(emb + bis[j] * DD);
        #pragma unroll
        for (int c4 = 0; c4 < 16; ++c4) {
            float4 e = brow[c4];
            float eq[4] = { e.x, e.y, e.z, e.w };
            #pragma unroll
            for (int q = 0; q < 4; ++q) {
                const int c = c4 * 4 + q;
                float dd = eq[q] - zr[j][c];
                lsum = fmaf(dd, dd, lsum);
                op[(size_t)c << 16] = eq[q];
            }
        }
        out[IDX_OFF + ((size_t)b << 16) + sp0 + j * 256] = (float)bis[j];
    }

    #pragma unroll
    for (int off = 32; off > 0; off >>= 1) lsum += __shfl_down(lsum, off);
    if ((tid & 63) == 0)
        atomicAdd((double*)ws, (double)lsum);          // fp64 final accumulation
}

__global__ void vq_finalize(const float* __restrict__ ws, float* __restrict__ out) {
    out[LOSS_OFF] = (float)(((const double*)ws)[0] * (1.25 / 33554432.0));
}

extern "C" void kernel_launch(void* const* d_in, const int* in_sizes, int n_in,
                              void* d_out, int out_size, void* d_ws, size_t ws_size,
                              hipStream_t stream) {
    const float* z   = (const float*)d_in[0];
    const float* emb = (const float*)d_in[1];
    float* out = (float*)d_out;
    float* ws  = (float*)d_ws;

    vq_ee<<<dim3(2), dim3(256), 0, stream>>>(emb, ws);
    vq_main<<<dim3(512), dim3(256), 0, stream>>>(z, emb, out, ws);
    vq_finalize<<<dim3(1), dim3(1), 0, stream>>>(ws, out);
}